// Round 2
// baseline (6076.233 us; speedup 1.0000x reference)
//
#include <hip/hip_runtime.h>

// KMEANS encode+decode: B=65536, G=256, K=512, fp32.
// R2: register-blocked fp32 SGEMM (M=65536,N=512,Kd=256) with fused argmin.
//   dist2[b,k] = (x2[b] - 2*xm[b,k]) + m2[k]; argmin ties -> first index.
// Accumulation orders kept identical to R1 (which matched ref exactly):
//   xm: k ascending fmac chain; x2: g ascending; m2: g ascending.

constexpr int BATCH = 65536;
constexpr int GDIM  = 256;   // GEMM K
constexpr int KDIM  = 512;   // GEMM N (codes)

constexpr int MT = 128, NT = 128, KP = 16;
constexpr int STR = 132;               // LDS panel row stride (words), padded
constexpr int NTILES = KDIM / NT;      // 4
constexpr int NPANEL = GDIM / KP;      // 16

// ---------------- helper kernels ----------------

__global__ void transpose_kernel(const float* __restrict__ mu, float* __restrict__ muT) {
    const int k = blockIdx.x, g = threadIdx.x;
    muT[k * GDIM + g] = mu[g * KDIM + k];
}

__global__ __launch_bounds__(256)
void x2m2_kernel(const float* __restrict__ images, const float* __restrict__ mu,
                 float* __restrict__ x2, float* __restrict__ m2) {
    const int tid = threadIdx.x;
    if (blockIdx.x < 256) {
        const int row = blockIdx.x * 256 + tid;
        const float4* p = (const float4*)(images + (size_t)row * GDIM);
        float s = 0.f;
        #pragma unroll 8
        for (int i = 0; i < GDIM / 4; ++i) {
            const float4 v = p[i];
            s += v.x * v.x; s += v.y * v.y; s += v.z * v.z; s += v.w * v.w;
        }
        x2[row] = s;
    } else {
        float s0 = 0.f, s1 = 0.f;
        for (int g = 0; g < GDIM; ++g) {
            const float a = mu[(size_t)g * KDIM + tid];
            const float b = mu[(size_t)g * KDIM + tid + 256];
            s0 += a * a; s1 += b * b;
        }
        m2[tid] = s0; m2[tid + 256] = s1;
    }
}

// ---------------- main GEMM + per-tile argmin ----------------

__global__ __launch_bounds__(256, 4)
void gemm_argmin_kernel(const float* __restrict__ images, const float* __restrict__ mu,
                        const float* __restrict__ x2g, const float* __restrict__ m2g,
                        float* __restrict__ pd, int* __restrict__ pk) {
    __shared__ float As[2][KP * STR];   // [k][m] transposed, 132-word rows
    __shared__ float Bs[2][KP * STR];   // [k][n]

    const int tid = threadIdx.x;
    const int m0  = blockIdx.x * MT;
    const int n0  = blockIdx.y * NT;
    const int tx  = tid & 15;           // code group (8 codes)
    const int ty  = tid >> 4;           // row group (8 rows); wave-uniform-ish (4 values/wave)

    // staging coords
    const int cA = tid & 3,  mA = tid >> 2;    // A: k-chunk (float4), row 0..63 (+64)
    const int kB = tid >> 5, cB = tid & 31;    // B: k-row 0..7 (+8), n-chunk (float4)

    const float4* img4 = (const float4*)images;
    const float4* mu4  = (const float4*)mu;
    const size_t aIdx0 = (size_t)(m0 + mA) * (GDIM / 4) + cA;          // + p*4 per panel
    const size_t aIdx1 = aIdx0 + (size_t)64 * (GDIM / 4);
    const size_t bIdx0 = (size_t)kB * (KDIM / 4) + (n0 >> 2) + cB;     // + p*KP*128 per panel
    const size_t bIdx1 = bIdx0 + (size_t)8 * (KDIM / 4);

    float acc[8][8];
    #pragma unroll
    for (int r = 0; r < 8; ++r)
        #pragma unroll
        for (int c = 0; c < 8; ++c) acc[r][c] = 0.f;

    // prologue: stage panel 0
    float4 a0 = img4[aIdx0], a1 = img4[aIdx1];
    float4 b0 = mu4[bIdx0],  b1 = mu4[bIdx1];
    #pragma unroll
    for (int j = 0; j < 4; ++j) {
        As[0][(cA * 4 + j) * STR + mA]      = ((const float*)&a0)[j];
        As[0][(cA * 4 + j) * STR + mA + 64] = ((const float*)&a1)[j];
    }
    *(float4*)&Bs[0][kB * STR + cB * 4]       = b0;
    *(float4*)&Bs[0][(kB + 8) * STR + cB * 4] = b1;
    __syncthreads();

    for (int p = 0; p < NPANEL; ++p) {
        const int buf = p & 1;
        // prefetch panel p+1 into registers (overlaps compute below)
        if (p + 1 < NPANEL) {
            a0 = img4[aIdx0 + (size_t)(p + 1) * 4];
            a1 = img4[aIdx1 + (size_t)(p + 1) * 4];
            b0 = mu4[bIdx0 + (size_t)(p + 1) * (KP * KDIM / 4)];
            b1 = mu4[bIdx1 + (size_t)(p + 1) * (KP * KDIM / 4)];
        }
        // compute panel p (k ascending -> same accumulation order as R1)
        #pragma unroll
        for (int kk = 0; kk < KP; ++kk) {
            const float4 A0 = *(const float4*)&As[buf][kk * STR + ty * 8];
            const float4 A1 = *(const float4*)&As[buf][kk * STR + ty * 8 + 4];
            const float4 B0 = *(const float4*)&Bs[buf][kk * STR + tx * 8];
            const float4 B1 = *(const float4*)&Bs[buf][kk * STR + tx * 8 + 4];
            const float a_[8] = {A0.x, A0.y, A0.z, A0.w, A1.x, A1.y, A1.z, A1.w};
            const float b_[8] = {B0.x, B0.y, B0.z, B0.w, B1.x, B1.y, B1.z, B1.w};
            #pragma unroll
            for (int r = 0; r < 8; ++r)
                #pragma unroll
                for (int c = 0; c < 8; ++c)
                    acc[r][c] += a_[r] * b_[c];
        }
        // write prefetched panel p+1 to the other buffer (no race: distinct buf)
        if (p + 1 < NPANEL) {
            const int nb = (p + 1) & 1;
            #pragma unroll
            for (int j = 0; j < 4; ++j) {
                As[nb][(cA * 4 + j) * STR + mA]      = ((const float*)&a0)[j];
                As[nb][(cA * 4 + j) * STR + mA + 64] = ((const float*)&a1)[j];
            }
            *(float4*)&Bs[nb][kB * STR + cB * 4]       = b0;
            *(float4*)&Bs[nb][(kB + 8) * STR + cB * 4] = b1;
        }
        __syncthreads();
    }

    // ---- epilogue: distances + argmin over this block's 128 codes ----
    float x2v[8], m2v[8];
    #pragma unroll
    for (int r = 0; r < 8; ++r) x2v[r] = x2g[m0 + ty * 8 + r];
    #pragma unroll
    for (int c = 0; c < 8; ++c) m2v[c] = m2g[n0 + tx * 8 + c];

    float* rd = (float*)As;   // 128x16 floats (2048) fits in As
    int*   rk = (int*)Bs;
    #pragma unroll
    for (int r = 0; r < 8; ++r) {
        float bd = 3.402823466e+38f; int bk = 0;
        #pragma unroll
        for (int c = 0; c < 8; ++c) {      // ascending code, strict '<' => first
            const float t = x2v[r] - 2.0f * acc[r][c];
            const float d = t + m2v[c];
            if (d < bd) { bd = d; bk = n0 + tx * 8 + c; }
        }
        rd[(ty * 8 + r) * 16 + tx] = bd;
        rk[(ty * 8 + r) * 16 + tx] = bk;
    }
    __syncthreads();
    if (tid < MT) {
        float bd = rd[tid * 16]; int bk = rk[tid * 16];
        #pragma unroll
        for (int t = 1; t < 16; ++t) {     // ascending tx = ascending code blocks
            const float d = rd[tid * 16 + t];
            if (d < bd) { bd = d; bk = rk[tid * 16 + t]; }
        }
        pd[(size_t)blockIdx.y * BATCH + m0 + tid] = bd;
        pk[(size_t)blockIdx.y * BATCH + m0 + tid] = bk;
    }
}

// ---------------- final cross-tile argmin + recon ----------------

__global__ __launch_bounds__(256)
void final_kernel(const float* __restrict__ pd, const int* __restrict__ pk,
                  const float* __restrict__ muT, float* __restrict__ out) {
    __shared__ int kb[64];
    const int tid = threadIdx.x;
    const long long b0 = (long long)blockIdx.x * 64;
    if (tid < 64) {
        const size_t row = (size_t)b0 + tid;
        float bd = pd[row]; int bk = pk[row];
        #pragma unroll
        for (int t = 1; t < NTILES; ++t) {   // ascending tile, strict '<'
            const float d = pd[(size_t)t * BATCH + row];
            if (d < bd) { bd = d; bk = pk[(size_t)t * BATCH + row]; }
        }
        kb[tid] = bk;
    }
    __syncthreads();
    float4* out4 = (float4*)(out + b0 * GDIM);
    const float4* muT4 = (const float4*)muT;
    #pragma unroll
    for (int i = 0; i < 16; ++i) {
        const int idx = tid + i * 256;
        const int rr = idx >> 6, cc = idx & 63;
        out4[idx] = muT4[(size_t)kb[rr] * (GDIM / 4) + cc];
    }
}

// ---------------- fallback (R1 kernel, no workspace) ----------------

constexpr int FROWS = 64, FXSTR = GDIM + 1;

__global__ __launch_bounds__(256)
void kmeans_fallback(const float* __restrict__ images, const float* __restrict__ mu,
                     float* __restrict__ out) {
    __shared__ float xs[FROWS * FXSTR];
    __shared__ float m2s[KDIM];
    __shared__ float bd_s[4][FROWS];
    __shared__ int   bk_s[4][FROWS];
    __shared__ int   kbest_s[FROWS];
    const int tid = threadIdx.x;
    const long long b0 = (long long)blockIdx.x * FROWS;
    {
        const float4* img4 = (const float4*)(images + b0 * GDIM);
        #pragma unroll
        for (int i = 0; i < 16; ++i) {
            const int idx = tid + i * 256;
            const int r = idx >> 6, c = idx & 63;
            const float4 v = img4[idx];
            float* dst = &xs[r * FXSTR + c * 4];
            dst[0] = v.x; dst[1] = v.y; dst[2] = v.z; dst[3] = v.w;
        }
    }
    {
        float s0 = 0.f, s1 = 0.f;
        for (int g = 0; g < GDIM; ++g) {
            const float a = mu[(size_t)g * KDIM + tid];
            const float b = mu[(size_t)g * KDIM + tid + 256];
            s0 += a * a; s1 += b * b;
        }
        m2s[tid] = s0; m2s[tid + 256] = s1;
    }
    __syncthreads();
    const int r = tid & (FROWS - 1), ch = tid >> 6;
    const float* xrow = &xs[r * FXSTR];
    float x2 = 0.f;
    #pragma unroll 8
    for (int g = 0; g < GDIM; ++g) x2 += xrow[g] * xrow[g];
    float bestd = 3.402823466e+38f; int bestk = 0;
    const int k0base = ch * (KDIM / 4);
    for (int kt = 0; kt < KDIM / 4; kt += 8) {
        const int k0 = k0base + kt;
        float a8[8];
        #pragma unroll
        for (int j = 0; j < 8; ++j) a8[j] = 0.f;
        const float* mp = mu + k0;
        #pragma unroll 4
        for (int g = 0; g < GDIM; ++g) {
            const float xv = xrow[g];
            const float4 a = *(const float4*)(mp + (size_t)g * KDIM);
            const float4 b = *(const float4*)(mp + (size_t)g * KDIM + 4);
            a8[0] += xv * a.x; a8[1] += xv * a.y; a8[2] += xv * a.z; a8[3] += xv * a.w;
            a8[4] += xv * b.x; a8[5] += xv * b.y; a8[6] += xv * b.z; a8[7] += xv * b.w;
        }
        #pragma unroll
        for (int j = 0; j < 8; ++j) {
            const float t = x2 - 2.0f * a8[j];
            const float d = t + m2s[k0 + j];
            if (d < bestd) { bestd = d; bestk = k0 + j; }
        }
    }
    bd_s[ch][r] = bestd; bk_s[ch][r] = bestk;
    __syncthreads();
    if (tid < FROWS) {
        float bd = bd_s[0][tid]; int bk = bk_s[0][tid];
        #pragma unroll
        for (int c = 1; c < 4; ++c)
            if (bd_s[c][tid] < bd) { bd = bd_s[c][tid]; bk = bk_s[c][tid]; }
        kbest_s[tid] = bk;
    }
    __syncthreads();
    for (int i = tid; i < FROWS * GDIM; i += 256) {
        const int rr = i >> 8, gg = i & (GDIM - 1);
        out[b0 * GDIM + i] = mu[(size_t)gg * KDIM + kbest_s[rr]];
    }
}

// ---------------- launch ----------------

extern "C" void kernel_launch(void* const* d_in, const int* in_sizes, int n_in,
                              void* d_out, int out_size, void* d_ws, size_t ws_size,
                              hipStream_t stream) {
    const float* images = (const float*)d_in[0];
    const float* mu     = (const float*)d_in[1];
    float* out = (float*)d_out;

    float* ws  = (float*)d_ws;
    float* muT = ws;                        // 131072 floats
    float* x2  = ws + 131072;               // 65536
    float* m2  = ws + 196608;               // 512
    float* pd  = ws + 197120;               // 4*65536 = 262144
    int*   pk  = (int*)(ws + 459264);       // 262144
    const size_t need = (size_t)(459264 + 262144) * sizeof(float);

    if (d_ws != nullptr && ws_size >= need) {
        transpose_kernel<<<KDIM, GDIM, 0, stream>>>(mu, muT);
        x2m2_kernel<<<257, 256, 0, stream>>>(images, mu, x2, m2);
        gemm_argmin_kernel<<<dim3(BATCH / MT, NTILES), 256, 0, stream>>>(
            images, mu, x2, m2, pd, pk);
        final_kernel<<<BATCH / 64, 256, 0, stream>>>(pd, pk, muT, out);
    } else {
        kmeans_fallback<<<BATCH / 64, 256, 0, stream>>>(images, mu, out);
    }
}

// Round 3
// 1395.102 us; speedup vs baseline: 4.3554x; 4.3554x over previous
//
#include <hip/hip_runtime.h>

// KMEANS encode+decode: B=65536, G=256, K=512, fp32.
// R3: fp32 SGEMM (M=65536,N=512,Kd=256) + fused argmin.  Fixes R2's
// register spill: launch_bounds(256,2) (VGPR cap 256) and NO address-taken
// locals anywhere in the hot kernel (explicit .x/.y/.z/.w everywhere).
// dist2 = (x2 - 2*xm) + m2, ascending-k strict '<' argmin (ties -> first),
// identical numerics to the passing R1/R2 kernels.

constexpr int BATCH = 65536;
constexpr int GDIM  = 256;   // GEMM K
constexpr int KDIM  = 512;   // GEMM N (codes)

constexpr int MT = 128, NT = 128, KP = 16;
constexpr int STR = 132;               // padded LDS row stride (words)
constexpr int NTILES = KDIM / NT;      // 4
constexpr int NPANEL = GDIM / KP;      // 16

// ---------------- helper kernels ----------------

__global__ void transpose_kernel(const float* __restrict__ mu, float* __restrict__ muT) {
    const int k = blockIdx.x, g = threadIdx.x;
    muT[k * GDIM + g] = mu[g * KDIM + k];
}

__global__ __launch_bounds__(256)
void x2m2_kernel(const float* __restrict__ images, const float* __restrict__ mu,
                 float* __restrict__ x2, float* __restrict__ m2) {
    const int tid = threadIdx.x;
    if (blockIdx.x < 256) {
        const int row = blockIdx.x * 256 + tid;
        const float4* p = (const float4*)(images + (size_t)row * GDIM);
        float s = 0.f;
        #pragma unroll 8
        for (int i = 0; i < GDIM / 4; ++i) {
            const float4 v = p[i];
            s += v.x * v.x; s += v.y * v.y; s += v.z * v.z; s += v.w * v.w;
        }
        x2[row] = s;
    } else {
        float s0 = 0.f, s1 = 0.f;
        for (int g = 0; g < GDIM; ++g) {
            const float a = mu[(size_t)g * KDIM + tid];
            const float b = mu[(size_t)g * KDIM + tid + 256];
            s0 += a * a; s1 += b * b;
        }
        m2[tid] = s0; m2[tid + 256] = s1;
    }
}

// ---------------- main GEMM + per-tile argmin ----------------

#define FMAROW(R, AV)                                          \
    acc[R][0].x += (AV) * B0.x; acc[R][0].y += (AV) * B0.y;    \
    acc[R][0].z += (AV) * B0.z; acc[R][0].w += (AV) * B0.w;    \
    acc[R][1].x += (AV) * B1.x; acc[R][1].y += (AV) * B1.y;    \
    acc[R][1].z += (AV) * B1.z; acc[R][1].w += (AV) * B1.w;

#define DISTC(ACC, M2, C)                                      \
    { const float t = x2r - 2.0f * (ACC);                      \
      const float d = t + (M2);                                \
      if (d < bd) { bd = d; bk = kc0 + (C); } }

#define ROWEP(R, X2)                                           \
    { const float x2r = (X2);                                  \
      float bd = 3.402823466e+38f; int bk = 0;                 \
      DISTC(acc[R][0].x, m2a.x, 0)                             \
      DISTC(acc[R][0].y, m2a.y, 1)                             \
      DISTC(acc[R][0].z, m2a.z, 2)                             \
      DISTC(acc[R][0].w, m2a.w, 3)                             \
      DISTC(acc[R][1].x, m2b.x, 4)                             \
      DISTC(acc[R][1].y, m2b.y, 5)                             \
      DISTC(acc[R][1].z, m2b.z, 6)                             \
      DISTC(acc[R][1].w, m2b.w, 7)                             \
      rd[(ty * 8 + (R)) * 16 + tx] = bd;                       \
      rk[(ty * 8 + (R)) * 16 + tx] = bk; }

#define STAGE_A(BUF, VA0, VA1)                                 \
    As[BUF][(cA * 4 + 0) * STR + mA]      = (VA0).x;           \
    As[BUF][(cA * 4 + 1) * STR + mA]      = (VA0).y;           \
    As[BUF][(cA * 4 + 2) * STR + mA]      = (VA0).z;           \
    As[BUF][(cA * 4 + 3) * STR + mA]      = (VA0).w;           \
    As[BUF][(cA * 4 + 0) * STR + mA + 64] = (VA1).x;           \
    As[BUF][(cA * 4 + 1) * STR + mA + 64] = (VA1).y;           \
    As[BUF][(cA * 4 + 2) * STR + mA + 64] = (VA1).z;           \
    As[BUF][(cA * 4 + 3) * STR + mA + 64] = (VA1).w;

__global__ __launch_bounds__(256, 2)
void gemm_argmin_kernel(const float* __restrict__ images, const float* __restrict__ mu,
                        const float* __restrict__ x2g, const float* __restrict__ m2g,
                        float* __restrict__ pd, int* __restrict__ pk) {
    __shared__ float As[2][KP * STR];
    __shared__ float Bs[2][KP * STR];

    const int tid = threadIdx.x;
    const int m0  = blockIdx.x * MT;
    const int n0  = blockIdx.y * NT;
    const int tx  = tid & 15;           // code group (8 codes)
    const int ty  = tid >> 4;           // row group (8 rows)

    const int cA = tid & 3,  mA = tid >> 2;    // A staging coords
    const int kB = tid >> 5, cB = tid & 31;    // B staging coords

    const float4* img4 = (const float4*)images;
    const float4* mu4  = (const float4*)mu;
    const size_t aIdx0 = (size_t)(m0 + mA) * (GDIM / 4) + cA;
    const size_t aIdx1 = aIdx0 + (size_t)64 * (GDIM / 4);
    const size_t bIdx0 = (size_t)kB * (KDIM / 4) + (n0 >> 2) + cB;
    const size_t bIdx1 = bIdx0 + (size_t)8 * (KDIM / 4);

    float4 acc[8][2];
    #pragma unroll
    for (int r = 0; r < 8; ++r) {
        acc[r][0] = make_float4(0.f, 0.f, 0.f, 0.f);
        acc[r][1] = make_float4(0.f, 0.f, 0.f, 0.f);
    }

    // prologue: stage panel 0
    float4 pa0 = img4[aIdx0], pa1 = img4[aIdx1];
    float4 pb0 = mu4[bIdx0],  pb1 = mu4[bIdx1];
    STAGE_A(0, pa0, pa1)
    *(float4*)&Bs[0][kB * STR + cB * 4]       = pb0;
    *(float4*)&Bs[0][(kB + 8) * STR + cB * 4] = pb1;
    __syncthreads();

    for (int p = 0; p < NPANEL; ++p) {
        const int buf = p & 1;
        if (p + 1 < NPANEL) {   // register prefetch of panel p+1
            pa0 = img4[aIdx0 + (size_t)(p + 1) * 4];
            pa1 = img4[aIdx1 + (size_t)(p + 1) * 4];
            pb0 = mu4[bIdx0 + (size_t)(p + 1) * (KP * KDIM / 4)];
            pb1 = mu4[bIdx1 + (size_t)(p + 1) * (KP * KDIM / 4)];
        }
        #pragma unroll
        for (int kk = 0; kk < KP; ++kk) {   // k ascending: same accum order as R1
            const float4 A0 = *(const float4*)&As[buf][kk * STR + ty * 8];
            const float4 A1 = *(const float4*)&As[buf][kk * STR + ty * 8 + 4];
            const float4 B0 = *(const float4*)&Bs[buf][kk * STR + tx * 8];
            const float4 B1 = *(const float4*)&Bs[buf][kk * STR + tx * 8 + 4];
            FMAROW(0, A0.x) FMAROW(1, A0.y) FMAROW(2, A0.z) FMAROW(3, A0.w)
            FMAROW(4, A1.x) FMAROW(5, A1.y) FMAROW(6, A1.z) FMAROW(7, A1.w)
        }
        if (p + 1 < NPANEL) {
            const int nb = (p + 1) & 1;
            STAGE_A(nb, pa0, pa1)
            *(float4*)&Bs[nb][kB * STR + cB * 4]       = pb0;
            *(float4*)&Bs[nb][(kB + 8) * STR + cB * 4] = pb1;
        }
        __syncthreads();
    }

    // ---- epilogue: distances + argmin over this block's 128 codes ----
    const float4 x2a = *(const float4*)&x2g[m0 + ty * 8];
    const float4 x2b = *(const float4*)&x2g[m0 + ty * 8 + 4];
    const float4 m2a = *(const float4*)&m2g[n0 + tx * 8];
    const float4 m2b = *(const float4*)&m2g[n0 + tx * 8 + 4];
    const int kc0 = n0 + tx * 8;

    float* rd = (float*)As;   // 128x16 floats, fits
    int*   rk = (int*)Bs;
    ROWEP(0, x2a.x) ROWEP(1, x2a.y) ROWEP(2, x2a.z) ROWEP(3, x2a.w)
    ROWEP(4, x2b.x) ROWEP(5, x2b.y) ROWEP(6, x2b.z) ROWEP(7, x2b.w)
    __syncthreads();

    if (tid < MT) {
        float bd = rd[tid * 16]; int bk = rk[tid * 16];
        #pragma unroll
        for (int t = 1; t < 16; ++t) {     // ascending tx = ascending codes
            const float d = rd[tid * 16 + t];
            if (d < bd) { bd = d; bk = rk[tid * 16 + t]; }
        }
        pd[(size_t)blockIdx.y * BATCH + m0 + tid] = bd;
        pk[(size_t)blockIdx.y * BATCH + m0 + tid] = bk;
    }
}

// ---------------- final cross-tile argmin + recon ----------------

__global__ __launch_bounds__(256)
void final_kernel(const float* __restrict__ pd, const int* __restrict__ pk,
                  const float* __restrict__ muT, float* __restrict__ out) {
    __shared__ int kb[64];
    const int tid = threadIdx.x;
    const long long b0 = (long long)blockIdx.x * 64;
    if (tid < 64) {
        const size_t row = (size_t)b0 + tid;
        float bd = pd[row]; int bk = pk[row];
        #pragma unroll
        for (int t = 1; t < NTILES; ++t) {   // ascending tile, strict '<'
            const float d = pd[(size_t)t * BATCH + row];
            if (d < bd) { bd = d; bk = pk[(size_t)t * BATCH + row]; }
        }
        kb[tid] = bk;
    }
    __syncthreads();
    float4* out4 = (float4*)(out + b0 * GDIM);
    const float4* muT4 = (const float4*)muT;
    #pragma unroll
    for (int i = 0; i < 16; ++i) {
        const int idx = tid + i * 256;
        const int rr = idx >> 6, cc = idx & 63;
        out4[idx] = muT4[(size_t)kb[rr] * (GDIM / 4) + cc];
    }
}

// ---------------- fallback (R1 kernel, no workspace) ----------------

constexpr int FROWS = 64, FXSTR = GDIM + 1;

__global__ __launch_bounds__(256)
void kmeans_fallback(const float* __restrict__ images, const float* __restrict__ mu,
                     float* __restrict__ out) {
    __shared__ float xs[FROWS * FXSTR];
    __shared__ float m2s[KDIM];
    __shared__ float bd_s[4][FROWS];
    __shared__ int   bk_s[4][FROWS];
    __shared__ int   kbest_s[FROWS];
    const int tid = threadIdx.x;
    const long long b0 = (long long)blockIdx.x * FROWS;
    {
        const float4* img4 = (const float4*)(images + b0 * GDIM);
        #pragma unroll
        for (int i = 0; i < 16; ++i) {
            const int idx = tid + i * 256;
            const int r = idx >> 6, c = idx & 63;
            const float4 v = img4[idx];
            float* dst = &xs[r * FXSTR + c * 4];
            dst[0] = v.x; dst[1] = v.y; dst[2] = v.z; dst[3] = v.w;
        }
    }
    {
        float s0 = 0.f, s1 = 0.f;
        for (int g = 0; g < GDIM; ++g) {
            const float a = mu[(size_t)g * KDIM + tid];
            const float b = mu[(size_t)g * KDIM + tid + 256];
            s0 += a * a; s1 += b * b;
        }
        m2s[tid] = s0; m2s[tid + 256] = s1;
    }
    __syncthreads();
    const int r = tid & (FROWS - 1), ch = tid >> 6;
    const float* xrow = &xs[r * FXSTR];
    float x2 = 0.f;
    #pragma unroll 8
    for (int g = 0; g < GDIM; ++g) x2 += xrow[g] * xrow[g];
    float bestd = 3.402823466e+38f; int bestk = 0;
    const int k0base = ch * (KDIM / 4);
    for (int kt = 0; kt < KDIM / 4; kt += 8) {
        const int k0 = k0base + kt;
        float a8[8];
        #pragma unroll
        for (int j = 0; j < 8; ++j) a8[j] = 0.f;
        const float* mp = mu + k0;
        #pragma unroll 4
        for (int g = 0; g < GDIM; ++g) {
            const float xv = xrow[g];
            const float4 a = *(const float4*)(mp + (size_t)g * KDIM);
            const float4 b = *(const float4*)(mp + (size_t)g * KDIM + 4);
            a8[0] += xv * a.x; a8[1] += xv * a.y; a8[2] += xv * a.z; a8[3] += xv * a.w;
            a8[4] += xv * b.x; a8[5] += xv * b.y; a8[6] += xv * b.z; a8[7] += xv * b.w;
        }
        #pragma unroll
        for (int j = 0; j < 8; ++j) {
            const float t = x2 - 2.0f * a8[j];
            const float d = t + m2s[k0 + j];
            if (d < bestd) { bestd = d; bestk = k0 + j; }
        }
    }
    bd_s[ch][r] = bestd; bk_s[ch][r] = bestk;
    __syncthreads();
    if (tid < FROWS) {
        float bd = bd_s[0][tid]; int bk = bk_s[0][tid];
        #pragma unroll
        for (int c = 1; c < 4; ++c)
            if (bd_s[c][tid] < bd) { bd = bd_s[c][tid]; bk = bk_s[c][tid]; }
        kbest_s[tid] = bk;
    }
    __syncthreads();
    for (int i = tid; i < FROWS * GDIM; i += 256) {
        const int rr = i >> 8, gg = i & (GDIM - 1);
        out[b0 * GDIM + i] = mu[(size_t)gg * KDIM + kbest_s[rr]];
    }
}

// ---------------- launch ----------------

extern "C" void kernel_launch(void* const* d_in, const int* in_sizes, int n_in,
                              void* d_out, int out_size, void* d_ws, size_t ws_size,
                              hipStream_t stream) {
    const float* images = (const float*)d_in[0];
    const float* mu     = (const float*)d_in[1];
    float* out = (float*)d_out;

    float* ws  = (float*)d_ws;
    float* muT = ws;                        // 131072 floats
    float* x2  = ws + 131072;               // 65536
    float* m2  = ws + 196608;               // 512
    float* pd  = ws + 197120;               // 4*65536 = 262144
    int*   pk  = (int*)(ws + 459264);       // 262144
    const size_t need = (size_t)(459264 + 262144) * sizeof(float);

    if (d_ws != nullptr && ws_size >= need) {
        transpose_kernel<<<KDIM, GDIM, 0, stream>>>(mu, muT);
        x2m2_kernel<<<257, 256, 0, stream>>>(images, mu, x2, m2);
        gemm_argmin_kernel<<<dim3(BATCH / MT, NTILES), 256, 0, stream>>>(
            images, mu, x2, m2, pd, pk);
        final_kernel<<<BATCH / 64, 256, 0, stream>>>(pd, pk, muT, out);
    } else {
        kmeans_fallback<<<BATCH / 64, 256, 0, stream>>>(images, mu, out);
    }
}

// Round 4
// 327.022 us; speedup vs baseline: 18.5805x; 4.2661x over previous
//
#include <hip/hip_runtime.h>

// KMEANS encode+decode: B=65536, G=256, K=512, fp32.
// R4: fp16-split MFMA GEMM (xm = xh*mh + xh*ml + xl*mh via 3 chained
// mfma_f32_16x16x32_f16; dropped xl*ml <= ~2e-5) + best/2nd-best tracking.
// Rows with gap < TAU are re-solved exactly in R1 fp32 order by a rescue
// kernel (R1 ordering matched np with absmax 0.0 in rounds 1-3).
// No LDS / no barriers in the GEMM K-loop: A coalesced from global fp32 with
// in-register split; B from a pre-swizzled packed fp16 hi/lo layout (L2-hot).

constexpr int BATCH = 65536;
constexpr int GDIM  = 256;   // GEMM K (features)
constexpr int KDIM  = 512;   // GEMM N (codes)
constexpr float TAU = 4e-3f;

typedef _Float16 halfx8 __attribute__((ext_vector_type(8)));
typedef float    floatx4 __attribute__((ext_vector_type(4)));

// ---------------- prep kernels ----------------

__global__ void transpose_kernel(const float* __restrict__ mu, float* __restrict__ muT,
                                 int* __restrict__ rcount) {
    const int k = blockIdx.x, g = threadIdx.x;
    muT[k * GDIM + g] = mu[g * KDIM + k];
    if (k == 0 && g == 0) *rcount = 0;
}

__global__ __launch_bounds__(256)
void x2m2_kernel(const float* __restrict__ images, const float* __restrict__ mu,
                 float* __restrict__ x2, float* __restrict__ m2) {
    const int tid = threadIdx.x;
    if (blockIdx.x < 256) {
        const int row = blockIdx.x * 256 + tid;
        const float4* p = (const float4*)(images + (size_t)row * GDIM);
        float s = 0.f;
        #pragma unroll 8
        for (int i = 0; i < GDIM / 4; ++i) {
            const float4 v = p[i];
            s += v.x * v.x; s += v.y * v.y; s += v.z * v.z; s += v.w * v.w;
        }
        x2[row] = s;
    } else {
        float s0 = 0.f, s1 = 0.f;
        for (int g = 0; g < GDIM; ++g) {
            const float a = mu[(size_t)g * KDIM + tid];
            const float b = mu[(size_t)g * KDIM + tid + 256];
            s0 += a * a; s1 += b * b;
        }
        m2[tid] = s0; m2[tid + 256] = s1;
    }
}

// Packed B layout: vec index ((nf*8 + p)*4 + q)*16 + n15 holds 8 halves
// (k = p*32 + q*8 + j) of column n = nf*16 + n15.
__global__ __launch_bounds__(256)
void prep_pack_kernel(const float* __restrict__ mu,
                      halfx8* __restrict__ packh, halfx8* __restrict__ packl) {
    const int gid = blockIdx.x * 256 + threadIdx.x;   // [0, 16384)
    const int n15 = gid & 15;
    const int q   = (gid >> 4) & 3;
    const int p   = (gid >> 6) & 7;
    const int nf  = gid >> 9;
    const int n   = nf * 16 + n15;
    const int k0  = p * 32 + q * 8;
    halfx8 hv, lv;
    #pragma unroll
    for (int j = 0; j < 8; ++j) {
        const float v = mu[(size_t)(k0 + j) * KDIM + n];
        const _Float16 h = (_Float16)v;
        hv[j] = h;
        lv[j] = (_Float16)(v - (float)h);
    }
    packh[gid] = hv;
    packl[gid] = lv;
}

// ---------------- main MFMA GEMM + argmin + gap flagging ----------------

#define SPLIT1(H, L, X) { const _Float16 h_ = (_Float16)(X); (H) = h_; (L) = (_Float16)((X) - (float)h_); }

__global__ __launch_bounds__(256) __attribute__((amdgpu_waves_per_eu(2, 2)))
void gemm_argmin_mfma(const float* __restrict__ images,
                      const halfx8* __restrict__ packh,
                      const halfx8* __restrict__ packl,
                      const float* __restrict__ x2g, const float* __restrict__ m2g,
                      int* __restrict__ kbest, int* __restrict__ rlist,
                      int* __restrict__ rcount) {
    __shared__ float sd1[4][64];
    __shared__ float sd2[4][64];
    __shared__ int   sk1[4][64];

    const int tid  = threadIdx.x;
    const int wave = tid >> 6;
    const int lane = tid & 63;
    const int q    = lane >> 4;
    const int l15  = lane & 15;
    const int m0   = blockIdx.x * 64;

    floatx4 acc[4][8] = {};

    // A row bases: row = m0 + mf*16 + l15 (A-frag: m = lane&15, k = q*8 + j)
    const float* arow0 = images + (size_t)(m0 + l15) * GDIM + q * 8;
    const float* arow1 = arow0 + (size_t)16 * GDIM;
    const float* arow2 = arow0 + (size_t)32 * GDIM;
    const float* arow3 = arow0 + (size_t)48 * GDIM;

    for (int p = 0; p < 8; ++p) {
        halfx8 Ah[4], Al[4];
        #pragma unroll
        for (int mf = 0; mf < 4; ++mf) {
            const float* ap = (mf == 0) ? arow0 : (mf == 1) ? arow1 : (mf == 2) ? arow2 : arow3;
            const float4 v0 = *(const float4*)(ap + p * 32);
            const float4 v1 = *(const float4*)(ap + p * 32 + 4);
            SPLIT1(Ah[mf][0], Al[mf][0], v0.x)
            SPLIT1(Ah[mf][1], Al[mf][1], v0.y)
            SPLIT1(Ah[mf][2], Al[mf][2], v0.z)
            SPLIT1(Ah[mf][3], Al[mf][3], v0.w)
            SPLIT1(Ah[mf][4], Al[mf][4], v1.x)
            SPLIT1(Ah[mf][5], Al[mf][5], v1.y)
            SPLIT1(Ah[mf][6], Al[mf][6], v1.z)
            SPLIT1(Ah[mf][7], Al[mf][7], v1.w)
        }
        #pragma unroll
        for (int nf = 0; nf < 8; ++nf) {
            const int nfg = wave * 8 + nf;
            const int bidx = ((nfg * 8 + p) * 4 + q) * 16 + l15;
            const halfx8 Bh = packh[bidx];
            const halfx8 Bl = packl[bidx];
            #pragma unroll
            for (int mf = 0; mf < 4; ++mf) {
                acc[mf][nf] = __builtin_amdgcn_mfma_f32_16x16x32_f16(Ah[mf], Bh, acc[mf][nf], 0, 0, 0);
                acc[mf][nf] = __builtin_amdgcn_mfma_f32_16x16x32_f16(Ah[mf], Bl, acc[mf][nf], 0, 0, 0);
                acc[mf][nf] = __builtin_amdgcn_mfma_f32_16x16x32_f16(Al[mf], Bh, acc[mf][nf], 0, 0, 0);
            }
        }
    }

    // ---- epilogue: C layout col = lane&15 (n_local), row = q*4 + reg (m_local)
    float x2v[4][4];
    #pragma unroll
    for (int mf = 0; mf < 4; ++mf)
        #pragma unroll
        for (int r = 0; r < 4; ++r)
            x2v[mf][r] = x2g[m0 + mf * 16 + q * 4 + r];
    float m2v[8];
    #pragma unroll
    for (int nf = 0; nf < 8; ++nf)
        m2v[nf] = m2g[wave * 128 + nf * 16 + l15];

    float d1[4][4], d2[4][4];
    int   k1[4][4];
    #pragma unroll
    for (int mf = 0; mf < 4; ++mf)
        #pragma unroll
        for (int r = 0; r < 4; ++r) { d1[mf][r] = 3.402823466e+38f; d2[mf][r] = 3.402823466e+38f; k1[mf][r] = 0; }

    #pragma unroll
    for (int nf = 0; nf < 8; ++nf) {          // ascending n within lane
        const int kc = wave * 128 + nf * 16 + l15;
        #pragma unroll
        for (int mf = 0; mf < 4; ++mf)
            #pragma unroll
            for (int r = 0; r < 4; ++r) {
                const float t = x2v[mf][r] - 2.0f * acc[mf][nf][r];
                const float d = t + m2v[nf];
                if (d < d1[mf][r]) { d2[mf][r] = d1[mf][r]; d1[mf][r] = d; k1[mf][r] = kc; }
                else if (d < d2[mf][r]) { d2[mf][r] = d; }
            }
    }

    // butterfly across the 16 lanes of each quad (bits 0..3); tie -> lower k
    #pragma unroll
    for (int s = 1; s < 16; s <<= 1) {
        #pragma unroll
        for (int mf = 0; mf < 4; ++mf)
            #pragma unroll
            for (int r = 0; r < 4; ++r) {
                const float od1 = __shfl_xor(d1[mf][r], s, 64);
                const int   ok1 = __shfl_xor(k1[mf][r], s, 64);
                const float od2 = __shfl_xor(d2[mf][r], s, 64);
                const bool take = (od1 < d1[mf][r]) || (od1 == d1[mf][r] && ok1 < k1[mf][r]);
                const float loser = take ? d1[mf][r] : od1;
                if (take) { d1[mf][r] = od1; k1[mf][r] = ok1; }
                const float m2x = (od2 < d2[mf][r]) ? od2 : d2[mf][r];
                d2[mf][r] = (loser < m2x) ? loser : m2x;
            }
    }

    if (l15 == 0) {
        #pragma unroll
        for (int mf = 0; mf < 4; ++mf)
            #pragma unroll
            for (int r = 0; r < 4; ++r) {
                const int ml = mf * 16 + q * 4 + r;
                sd1[wave][ml] = d1[mf][r];
                sd2[wave][ml] = d2[mf][r];
                sk1[wave][ml] = k1[mf][r];
            }
    }
    __syncthreads();

    if (tid < 64) {
        float D1 = sd1[0][tid], D2 = sd2[0][tid];
        int   K1 = sk1[0][tid];
        #pragma unroll
        for (int w = 1; w < 4; ++w) {          // ascending wave = ascending k
            const float od1 = sd1[w][tid], od2 = sd2[w][tid];
            const int   ok1 = sk1[w][tid];
            if (od1 < D1) { D2 = (D1 < od2) ? D1 : od2; D1 = od1; K1 = ok1; }
            else          { D2 = (od1 < D2) ? od1 : D2; }
        }
        kbest[m0 + tid] = K1;
        if (D2 - D1 < TAU) {
            const int i = atomicAdd(rcount, 1);
            rlist[i] = m0 + tid;
        }
    }
}

// ---------------- rescue: exact R1-order fp32 recompute for flagged rows ----

__global__ __launch_bounds__(256)
void rescue_kernel(const float* __restrict__ images, const float* __restrict__ mu,
                   const float* __restrict__ x2g, const float* __restrict__ m2g,
                   const int* __restrict__ rlist, const int* __restrict__ rcount,
                   int* __restrict__ kbest) {
    __shared__ float xs[GDIM];
    __shared__ float sd[256];
    __shared__ int   sk[256];
    const int tid = threadIdx.x;
    const int cnt = *rcount;
    for (int i = blockIdx.x; i < cnt; i += gridDim.x) {
        const int row = rlist[i];
        xs[tid] = images[(size_t)row * GDIM + tid];
        __syncthreads();
        const float x2 = x2g[row];
        // codes tid and tid+256, g-ascending single fp32 chain (R1 order)
        float dA, dB;
        {
            float s = 0.f;
            for (int g = 0; g < GDIM; ++g) s += xs[g] * mu[(size_t)g * KDIM + tid];
            dA = (x2 - 2.0f * s) + m2g[tid];
        }
        {
            float s = 0.f;
            for (int g = 0; g < GDIM; ++g) s += xs[g] * mu[(size_t)g * KDIM + tid + 256];
            dB = (x2 - 2.0f * s) + m2g[tid + 256];
        }
        float bd = dA; int bk = tid;
        if (dB < bd) { bd = dB; bk = tid + 256; }   // strict < keeps lower k
        sd[tid] = bd; sk[tid] = bk;
        __syncthreads();
        for (int s = 128; s > 0; s >>= 1) {
            if (tid < s) {
                const float db = sd[tid + s]; const int kb2 = sk[tid + s];
                if (db < sd[tid] || (db == sd[tid] && kb2 < sk[tid])) { sd[tid] = db; sk[tid] = kb2; }
            }
            __syncthreads();
        }
        if (tid == 0) kbest[row] = sk[0];
        __syncthreads();
    }
}

// ---------------- recon ----------------

__global__ __launch_bounds__(256)
void recon_kernel(const int* __restrict__ kbest, const float* __restrict__ muT,
                  float* __restrict__ out) {
    __shared__ int kb[64];
    const int tid = threadIdx.x;
    const long long b0 = (long long)blockIdx.x * 64;
    if (tid < 64) kb[tid] = kbest[b0 + tid];
    __syncthreads();
    float4* out4 = (float4*)(out + b0 * GDIM);
    const float4* muT4 = (const float4*)muT;
    #pragma unroll
    for (int i = 0; i < 16; ++i) {
        const int idx = tid + i * 256;
        const int rr = idx >> 6, cc = idx & 63;
        out4[idx] = muT4[(size_t)kb[rr] * (GDIM / 4) + cc];
    }
}

// ---------------- fallback (R1 kernel, no workspace) ----------------

constexpr int FROWS = 64, FXSTR = GDIM + 1;

__global__ __launch_bounds__(256)
void kmeans_fallback(const float* __restrict__ images, const float* __restrict__ mu,
                     float* __restrict__ out) {
    __shared__ float xs[FROWS * FXSTR];
    __shared__ float m2s[KDIM];
    __shared__ float bd_s[4][FROWS];
    __shared__ int   bk_s[4][FROWS];
    __shared__ int   kbest_s[FROWS];
    const int tid = threadIdx.x;
    const long long b0 = (long long)blockIdx.x * FROWS;
    {
        const float4* img4 = (const float4*)(images + b0 * GDIM);
        #pragma unroll
        for (int i = 0; i < 16; ++i) {
            const int idx = tid + i * 256;
            const int r = idx >> 6, c = idx & 63;
            const float4 v = img4[idx];
            float* dst = &xs[r * FXSTR + c * 4];
            dst[0] = v.x; dst[1] = v.y; dst[2] = v.z; dst[3] = v.w;
        }
    }
    {
        float s0 = 0.f, s1 = 0.f;
        for (int g = 0; g < GDIM; ++g) {
            const float a = mu[(size_t)g * KDIM + tid];
            const float b = mu[(size_t)g * KDIM + tid + 256];
            s0 += a * a; s1 += b * b;
        }
        m2s[tid] = s0; m2s[tid + 256] = s1;
    }
    __syncthreads();
    const int r = tid & (FROWS - 1), ch = tid >> 6;
    const float* xrow = &xs[r * FXSTR];
    float x2 = 0.f;
    #pragma unroll 8
    for (int g = 0; g < GDIM; ++g) x2 += xrow[g] * xrow[g];
    float bestd = 3.402823466e+38f; int bestk = 0;
    const int k0base = ch * (KDIM / 4);
    for (int kt = 0; kt < KDIM / 4; kt += 8) {
        const int k0 = k0base + kt;
        float a8[8];
        #pragma unroll
        for (int j = 0; j < 8; ++j) a8[j] = 0.f;
        const float* mp = mu + k0;
        #pragma unroll 4
        for (int g = 0; g < GDIM; ++g) {
            const float xv = xrow[g];
            const float4 a = *(const float4*)(mp + (size_t)g * KDIM);
            const float4 b = *(const float4*)(mp + (size_t)g * KDIM + 4);
            a8[0] += xv * a.x; a8[1] += xv * a.y; a8[2] += xv * a.z; a8[3] += xv * a.w;
            a8[4] += xv * b.x; a8[5] += xv * b.y; a8[6] += xv * b.z; a8[7] += xv * b.w;
        }
        #pragma unroll
        for (int j = 0; j < 8; ++j) {
            const float t = x2 - 2.0f * a8[j];
            const float d = t + m2s[k0 + j];
            if (d < bestd) { bestd = d; bestk = k0 + j; }
        }
    }
    bd_s[ch][r] = bestd; bk_s[ch][r] = bestk;
    __syncthreads();
    if (tid < FROWS) {
        float bd = bd_s[0][tid]; int bk = bk_s[0][tid];
        #pragma unroll
        for (int c = 1; c < 4; ++c)
            if (bd_s[c][tid] < bd) { bd = bd_s[c][tid]; bk = bk_s[c][tid]; }
        kbest_s[tid] = bk;
    }
    __syncthreads();
    for (int i = tid; i < FROWS * GDIM; i += 256) {
        const int rr = i >> 8, gg = i & (GDIM - 1);
        out[b0 * GDIM + i] = mu[(size_t)gg * KDIM + kbest_s[rr]];
    }
}

// ---------------- launch ----------------

extern "C" void kernel_launch(void* const* d_in, const int* in_sizes, int n_in,
                              void* d_out, int out_size, void* d_ws, size_t ws_size,
                              hipStream_t stream) {
    const float* images = (const float*)d_in[0];
    const float* mu     = (const float*)d_in[1];
    float* out = (float*)d_out;

    float* ws    = (float*)d_ws;
    float* muT   = ws;                         // 131072 floats
    float* x2    = ws + 131072;                // 65536
    float* m2    = ws + 196608;                // 512
    halfx8* packh = (halfx8*)(ws + 197120);    // 65536 floats (16384 vecs)
    halfx8* packl = (halfx8*)(ws + 262656);    // 65536 floats
    int*   kbest = (int*)(ws + 328192);        // 65536
    int*   rlist = (int*)(ws + 393728);        // 65536
    int*   rcount = (int*)(ws + 459264);       // 16
    const size_t need = (size_t)459280 * sizeof(float);

    if (d_ws != nullptr && ws_size >= need) {
        transpose_kernel<<<KDIM, GDIM, 0, stream>>>(mu, muT, rcount);
        x2m2_kernel<<<257, 256, 0, stream>>>(images, mu, x2, m2);
        prep_pack_kernel<<<64, 256, 0, stream>>>(mu, packh, packl);
        gemm_argmin_mfma<<<BATCH / 64, 256, 0, stream>>>(images, packh, packl,
                                                         x2, m2, kbest, rlist, rcount);
        rescue_kernel<<<64, 256, 0, stream>>>(images, mu, x2, m2, rlist, rcount, kbest);
        recon_kernel<<<BATCH / 64, 256, 0, stream>>>(kbest, muT, out);
    } else {
        kmeans_fallback<<<BATCH / 64, 256, 0, stream>>>(images, mu, out);
    }
}

// Round 5
// 228.944 us; speedup vs baseline: 26.5403x; 1.4284x over previous
//
#include <hip/hip_runtime.h>

// KMEANS encode+decode: B=65536, G=256, K=512, fp32.
// R5: fp16-split MFMA GEMM (hh+hl+lh chains, dropped xl*ml <= ~2e-5) ranking
// on s = m2 - 2*xm (x2 is row-constant => argmin-invariant). Best/2nd-best
// gap < TAU rows are re-solved exactly in R1 fp32 order (proved absmax 0.0
// in R1-R4) by a 1024-block rescue kernel. Recon fused into gemm epilogue;
// rescue overwrites its rows. 4 dispatches total.

constexpr int BATCH = 65536;
constexpr int GDIM  = 256;   // GEMM K (features)
constexpr int KDIM  = 512;   // GEMM N (codes)
constexpr float TAU = 2e-3f;

typedef _Float16 halfx8 __attribute__((ext_vector_type(8)));
typedef float    floatx4 __attribute__((ext_vector_type(4)));

// ---------------- prep: transpose + m2 (m2 in proven g-ascending order) ----

__global__ __launch_bounds__(256)
void prep_mu_kernel(const float* __restrict__ mu, float* __restrict__ muT,
                    float* __restrict__ m2) {
    const int tid = threadIdx.x;
    if (blockIdx.x < 512) {
        const int k = blockIdx.x;
        muT[k * GDIM + tid] = mu[(size_t)tid * KDIM + k];
    } else {
        float s0 = 0.f, s1 = 0.f;
        for (int g = 0; g < GDIM; ++g) {
            const float a = mu[(size_t)g * KDIM + tid];
            const float b = mu[(size_t)g * KDIM + tid + 256];
            s0 += a * a; s1 += b * b;
        }
        m2[tid] = s0; m2[tid + 256] = s1;
    }
}

// Packed B layout (verified R4): vec ((nf*8 + p)*4 + q)*16 + n15 holds 8
// halves (k = p*32 + q*8 + j) of column n = nf*16 + n15.
__global__ __launch_bounds__(256)
void prep_pack_kernel(const float* __restrict__ mu,
                      halfx8* __restrict__ packh, halfx8* __restrict__ packl,
                      int* __restrict__ rcount) {
    const int gid = blockIdx.x * 256 + threadIdx.x;   // [0, 16384)
    if (gid == 0) *rcount = 0;
    const int n15 = gid & 15;
    const int q   = (gid >> 4) & 3;
    const int p   = (gid >> 6) & 7;
    const int nf  = gid >> 9;
    const int n   = nf * 16 + n15;
    const int k0  = p * 32 + q * 8;
    halfx8 hv, lv;
    #pragma unroll
    for (int j = 0; j < 8; ++j) {
        const float v = mu[(size_t)(k0 + j) * KDIM + n];
        const _Float16 h = (_Float16)v;
        hv[j] = h;
        lv[j] = (_Float16)(v - (float)h);
    }
    packh[gid] = hv;
    packl[gid] = lv;
}

// ---------------- main MFMA GEMM + argmin + fused recon ----------------

#define SPLIT1(H, L, X) { const _Float16 h_ = (_Float16)(X); (H) = h_; (L) = (_Float16)((X) - (float)h_); }

__global__ __launch_bounds__(256) __attribute__((amdgpu_waves_per_eu(2, 2)))
void gemm_argmin_mfma(const float* __restrict__ images,
                      const halfx8* __restrict__ packh,
                      const halfx8* __restrict__ packl,
                      const float* __restrict__ m2g,
                      const float* __restrict__ muT,
                      float* __restrict__ out,
                      int* __restrict__ rlist, int* __restrict__ rcount) {
    __shared__ float sd1[4][64];
    __shared__ float sd2[4][64];
    __shared__ int   sk1[4][64];
    __shared__ int   kb[64];

    const int tid  = threadIdx.x;
    const int wave = tid >> 6;
    const int lane = tid & 63;
    const int q    = lane >> 4;
    const int l15  = lane & 15;
    const int m0   = blockIdx.x * 64;

    floatx4 acc[4][8] = {};

    // A row bases (A-frag: m = lane&15, k = q*8 + j); verified in R4.
    const float* arow0 = images + (size_t)(m0 + l15) * GDIM + q * 8;
    const float* arow1 = arow0 + (size_t)16 * GDIM;
    const float* arow2 = arow0 + (size_t)32 * GDIM;
    const float* arow3 = arow0 + (size_t)48 * GDIM;

    for (int p = 0; p < 8; ++p) {
        halfx8 Ah[4], Al[4];
        #pragma unroll
        for (int mf = 0; mf < 4; ++mf) {
            const float* ap = (mf == 0) ? arow0 : (mf == 1) ? arow1 : (mf == 2) ? arow2 : arow3;
            const float4 v0 = *(const float4*)(ap + p * 32);
            const float4 v1 = *(const float4*)(ap + p * 32 + 4);
            SPLIT1(Ah[mf][0], Al[mf][0], v0.x)
            SPLIT1(Ah[mf][1], Al[mf][1], v0.y)
            SPLIT1(Ah[mf][2], Al[mf][2], v0.z)
            SPLIT1(Ah[mf][3], Al[mf][3], v0.w)
            SPLIT1(Ah[mf][4], Al[mf][4], v1.x)
            SPLIT1(Ah[mf][5], Al[mf][5], v1.y)
            SPLIT1(Ah[mf][6], Al[mf][6], v1.z)
            SPLIT1(Ah[mf][7], Al[mf][7], v1.w)
        }
        #pragma unroll
        for (int nf = 0; nf < 8; ++nf) {
            const int nfg = wave * 8 + nf;
            const int bidx = ((nfg * 8 + p) * 4 + q) * 16 + l15;
            const halfx8 Bh = packh[bidx];
            const halfx8 Bl = packl[bidx];
            #pragma unroll
            for (int mf = 0; mf < 4; ++mf) {
                acc[mf][nf] = __builtin_amdgcn_mfma_f32_16x16x32_f16(Ah[mf], Bh, acc[mf][nf], 0, 0, 0);
                acc[mf][nf] = __builtin_amdgcn_mfma_f32_16x16x32_f16(Ah[mf], Bl, acc[mf][nf], 0, 0, 0);
                acc[mf][nf] = __builtin_amdgcn_mfma_f32_16x16x32_f16(Al[mf], Bh, acc[mf][nf], 0, 0, 0);
            }
        }
    }

    // ---- epilogue: rank on s = m2 - 2*xm (x2 row-constant, argmin-invariant)
    // C layout (verified R4): col = lane&15 (n_local), row = q*4 + reg.
    float m2v[8];
    #pragma unroll
    for (int nf = 0; nf < 8; ++nf)
        m2v[nf] = m2g[wave * 128 + nf * 16 + l15];

    float d1[4][4], d2[4][4];
    int   k1[4][4];
    #pragma unroll
    for (int mf = 0; mf < 4; ++mf)
        #pragma unroll
        for (int r = 0; r < 4; ++r) { d1[mf][r] = 3.402823466e+38f; d2[mf][r] = 3.402823466e+38f; k1[mf][r] = 0; }

    #pragma unroll
    for (int nf = 0; nf < 8; ++nf) {
        const int kc = wave * 128 + nf * 16 + l15;
        #pragma unroll
        for (int mf = 0; mf < 4; ++mf)
            #pragma unroll
            for (int r = 0; r < 4; ++r) {
                const float d = m2v[nf] - 2.0f * acc[mf][nf][r];
                if (d < d1[mf][r]) { d2[mf][r] = d1[mf][r]; d1[mf][r] = d; k1[mf][r] = kc; }
                else if (d < d2[mf][r]) { d2[mf][r] = d; }
            }
    }

    // butterfly across the 16 lanes of each quad; tie -> lower k
    #pragma unroll
    for (int s = 1; s < 16; s <<= 1) {
        #pragma unroll
        for (int mf = 0; mf < 4; ++mf)
            #pragma unroll
            for (int r = 0; r < 4; ++r) {
                const float od1 = __shfl_xor(d1[mf][r], s, 64);
                const int   ok1 = __shfl_xor(k1[mf][r], s, 64);
                const float od2 = __shfl_xor(d2[mf][r], s, 64);
                const bool take = (od1 < d1[mf][r]) || (od1 == d1[mf][r] && ok1 < k1[mf][r]);
                const float loser = take ? d1[mf][r] : od1;
                if (take) { d1[mf][r] = od1; k1[mf][r] = ok1; }
                const float m2x = (od2 < d2[mf][r]) ? od2 : d2[mf][r];
                d2[mf][r] = (loser < m2x) ? loser : m2x;
            }
    }

    if (l15 == 0) {
        #pragma unroll
        for (int mf = 0; mf < 4; ++mf)
            #pragma unroll
            for (int r = 0; r < 4; ++r) {
                const int ml = mf * 16 + q * 4 + r;
                sd1[wave][ml] = d1[mf][r];
                sd2[wave][ml] = d2[mf][r];
                sk1[wave][ml] = k1[mf][r];
            }
    }
    __syncthreads();

    if (tid < 64) {
        float D1 = sd1[0][tid], D2 = sd2[0][tid];
        int   K1 = sk1[0][tid];
        #pragma unroll
        for (int w = 1; w < 4; ++w) {          // ascending wave = ascending k
            const float od1 = sd1[w][tid], od2 = sd2[w][tid];
            const int   ok1 = sk1[w][tid];
            if (od1 < D1) { D2 = (D1 < od2) ? D1 : od2; D1 = od1; K1 = ok1; }
            else          { D2 = (od1 < D2) ? od1 : D2; }
        }
        kb[tid] = K1;
        if (D2 - D1 < TAU) {
            const int i = atomicAdd(rcount, 1);
            rlist[i] = m0 + tid;
        }
    }
    __syncthreads();

    // ---- fused recon: out rows from muT (L2-hot) ----
    float4* out4 = (float4*)(out + (size_t)m0 * GDIM);
    const float4* muT4 = (const float4*)muT;
    #pragma unroll
    for (int i = 0; i < 16; ++i) {
        const int idx = tid + i * 256;
        const int rr = idx >> 6, cc = idx & 63;
        out4[idx] = muT4[(size_t)kb[rr] * (GDIM / 4) + cc];
    }
}

// ---------------- rescue: exact R1-order fp32 recompute + recon ----------

__global__ __launch_bounds__(256)
void rescue_kernel(const float* __restrict__ images, const float* __restrict__ mu,
                   const float* __restrict__ m2g, const float* __restrict__ muT,
                   const int* __restrict__ rlist, const int* __restrict__ rcount,
                   float* __restrict__ out) {
    __shared__ float xs[GDIM];
    __shared__ float sd[256];
    __shared__ int   sk[256];
    const int tid = threadIdx.x;
    const int cnt = *rcount;
    for (int i = blockIdx.x; i < cnt; i += gridDim.x) {
        const int row = rlist[i];
        xs[tid] = images[(size_t)row * GDIM + tid];
        __syncthreads();
        // x2 in the proven g-ascending serial order
        float x2 = 0.f;
        for (int g = 0; g < GDIM; ++g) x2 += xs[g] * xs[g];
        // codes tid and tid+256: independent g-ascending fp32 chains (R1 order)
        float sA = 0.f, sB = 0.f;
        for (int g = 0; g < GDIM; ++g) {
            const float xv = xs[g];
            const float* mp = mu + (size_t)g * KDIM;
            sA += xv * mp[tid];
            sB += xv * mp[tid + 256];
        }
        const float dA = (x2 - 2.0f * sA) + m2g[tid];
        const float dB = (x2 - 2.0f * sB) + m2g[tid + 256];
        float bd = dA; int bk = tid;
        if (dB < bd) { bd = dB; bk = tid + 256; }   // strict < keeps lower k
        sd[tid] = bd; sk[tid] = bk;
        __syncthreads();
        for (int s = 128; s > 0; s >>= 1) {
            if (tid < s) {
                const float db = sd[tid + s]; const int kb2 = sk[tid + s];
                if (db < sd[tid] || (db == sd[tid] && kb2 < sk[tid])) { sd[tid] = db; sk[tid] = kb2; }
            }
            __syncthreads();
        }
        const int kwin = sk[0];
        out[(size_t)row * GDIM + tid] = muT[(size_t)kwin * GDIM + tid];
        __syncthreads();
    }
}

// ---------------- fallback (R1 kernel, no workspace) ----------------

constexpr int FROWS = 64, FXSTR = GDIM + 1;

__global__ __launch_bounds__(256)
void kmeans_fallback(const float* __restrict__ images, const float* __restrict__ mu,
                     float* __restrict__ out) {
    __shared__ float xs[FROWS * FXSTR];
    __shared__ float m2s[KDIM];
    __shared__ float bd_s[4][FROWS];
    __shared__ int   bk_s[4][FROWS];
    __shared__ int   kbest_s[FROWS];
    const int tid = threadIdx.x;
    const long long b0 = (long long)blockIdx.x * FROWS;
    {
        const float4* img4 = (const float4*)(images + b0 * GDIM);
        #pragma unroll
        for (int i = 0; i < 16; ++i) {
            const int idx = tid + i * 256;
            const int r = idx >> 6, c = idx & 63;
            const float4 v = img4[idx];
            float* dst = &xs[r * FXSTR + c * 4];
            dst[0] = v.x; dst[1] = v.y; dst[2] = v.z; dst[3] = v.w;
        }
    }
    {
        float s0 = 0.f, s1 = 0.f;
        for (int g = 0; g < GDIM; ++g) {
            const float a = mu[(size_t)g * KDIM + tid];
            const float b = mu[(size_t)g * KDIM + tid + 256];
            s0 += a * a; s1 += b * b;
        }
        m2s[tid] = s0; m2s[tid + 256] = s1;
    }
    __syncthreads();
    const int r = tid & (FROWS - 1), ch = tid >> 6;
    const float* xrow = &xs[r * FXSTR];
    float x2 = 0.f;
    #pragma unroll 8
    for (int g = 0; g < GDIM; ++g) x2 += xrow[g] * xrow[g];
    float bestd = 3.402823466e+38f; int bestk = 0;
    const int k0base = ch * (KDIM / 4);
    for (int kt = 0; kt < KDIM / 4; kt += 8) {
        const int k0 = k0base + kt;
        float a8[8];
        #pragma unroll
        for (int j = 0; j < 8; ++j) a8[j] = 0.f;
        const float* mp = mu + k0;
        #pragma unroll 4
        for (int g = 0; g < GDIM; ++g) {
            const float xv = xrow[g];
            const float4 a = *(const float4*)(mp + (size_t)g * KDIM);
            const float4 b = *(const float4*)(mp + (size_t)g * KDIM + 4);
            a8[0] += xv * a.x; a8[1] += xv * a.y; a8[2] += xv * a.z; a8[3] += xv * a.w;
            a8[4] += xv * b.x; a8[5] += xv * b.y; a8[6] += xv * b.z; a8[7] += xv * b.w;
        }
        #pragma unroll
        for (int j = 0; j < 8; ++j) {
            const float t = x2 - 2.0f * a8[j];
            const float d = t + m2s[k0 + j];
            if (d < bestd) { bestd = d; bestk = k0 + j; }
        }
    }
    bd_s[ch][r] = bestd; bk_s[ch][r] = bestk;
    __syncthreads();
    if (tid < FROWS) {
        float bd = bd_s[0][tid]; int bk = bk_s[0][tid];
        #pragma unroll
        for (int c = 1; c < 4; ++c)
            if (bd_s[c][tid] < bd) { bd = bd_s[c][tid]; bk = bk_s[c][tid]; }
        kbest_s[tid] = bk;
    }
    __syncthreads();
    for (int i = tid; i < FROWS * GDIM; i += 256) {
        const int rr = i >> 8, gg = i & (GDIM - 1);
        out[b0 * GDIM + i] = mu[(size_t)gg * KDIM + kbest_s[rr]];
    }
}

// ---------------- launch ----------------

extern "C" void kernel_launch(void* const* d_in, const int* in_sizes, int n_in,
                              void* d_out, int out_size, void* d_ws, size_t ws_size,
                              hipStream_t stream) {
    const float* images = (const float*)d_in[0];
    const float* mu     = (const float*)d_in[1];
    float* out = (float*)d_out;

    float* ws    = (float*)d_ws;
    float* muT   = ws;                          // 131072 floats
    float* m2    = ws + 131072;                 // 512
    halfx8* packh = (halfx8*)(ws + 131584);     // 65536 floats (16384 vecs)
    halfx8* packl = (halfx8*)(ws + 197120);     // 65536 floats
    int*   rlist = (int*)(ws + 262656);         // 65536
    int*   rcount = (int*)(ws + 328192);        // 16
    const size_t need = (size_t)328208 * sizeof(float);

    if (d_ws != nullptr && ws_size >= need) {
        prep_mu_kernel<<<513, 256, 0, stream>>>(mu, muT, m2);
        prep_pack_kernel<<<64, 256, 0, stream>>>(mu, packh, packl, rcount);
        gemm_argmin_mfma<<<BATCH / 64, 256, 0, stream>>>(images, packh, packl,
                                                         m2, muT, out, rlist, rcount);
        rescue_kernel<<<1024, 256, 0, stream>>>(images, mu, m2, muT, rlist, rcount, out);
    } else {
        kmeans_fallback<<<BATCH / 64, 256, 0, stream>>>(images, mu, out);
    }
}